// Round 2
// baseline (4994.895 us; speedup 1.0000x reference)
//
#include <hip/hip_runtime.h>
#include <cstdint>
#include <cstddef>

#define NB 16
#define NC 256
#define NK 8
#define NN 16384
#define NSTAGE 10
#define FKAPPA 20.0f

// ---------------------------------------------------------------------------
// init: broadcast mu_in [C*K] -> mu_cur [B][C][K]
__global__ __launch_bounds__(256) void k_init_mu(const float* __restrict__ mu_in,
                                                 float* __restrict__ mu_cur) {
    int i = blockIdx.x * 256 + threadIdx.x;
    mu_cur[i] = mu_in[i & (NC * NK - 1)];
}

// ---------------------------------------------------------------------------
// Fused stage: per block = (b, 64-n tile).
//  1. load x tile (global, coalesced) -> registers -> transposed LDS xt[n][c]
//     while accumulating dot partials vs LDS-staged mu (4 waves = 4 c-parts)
//  2. LDS-atomic reduce dot -> dz[n][k]; wave0: softmax over k, colsum atomics
//  3. accumulate phase: thread=c, num[c][k] += xt[n][c]*dz[n][k], global atomics
// z written to global only when WRITE_Z (last stage).
template <bool WRITE_Z>
__global__ __launch_bounds__(256) void k_stage(const float* __restrict__ x,
                                               const float* __restrict__ mu,
                                               float* __restrict__ num,
                                               float* __restrict__ colsum,
                                               float* __restrict__ zout) {
    const int b  = blockIdx.x >> 8;       // 256 n-tiles per b
    const int nt = blockIdx.x & 255;
    const int t  = threadIdx.x;
    const int n  = t & 63;                // lane within wave = n in tile
    const int p  = t >> 6;                // wave = c-partition (64 c's each)

    __shared__ __align__(16) float xt[64][257];   // transposed, padded: 65792 B
    __shared__ __align__(16) float smu[NC * NK];  // 8192 B
    __shared__ __align__(16) float dz[64][NK];    // dot, then z: 2048 B

    for (int i = t; i < NC * NK; i += 256) smu[i] = mu[b * NC * NK + i];
    if (t < 128) reinterpret_cast<float4*>(dz)[t] = make_float4(0.f, 0.f, 0.f, 0.f);
    __syncthreads();

    const int n0 = nt * 64;
    const float* xp = x + (size_t)b * NC * NN + n0 + n;

    float acc[NK];
    #pragma unroll
    for (int k = 0; k < NK; k++) acc[k] = 0.f;

    const int c0 = p * 64;
    #pragma unroll 8
    for (int ci = 0; ci < 64; ++ci) {
        const int c = c0 + ci;
        const float xv = xp[(size_t)c * NN];      // lanes n consecutive: 256B coalesced
        xt[n][c] = xv;                            // banks (n+c)%32: conflict-free
        const float4 m0 = *reinterpret_cast<const float4*>(&smu[c * NK]);
        const float4 m1 = *reinterpret_cast<const float4*>(&smu[c * NK + 4]);
        acc[0] += xv * m0.x; acc[1] += xv * m0.y; acc[2] += xv * m0.z; acc[3] += xv * m0.w;
        acc[4] += xv * m1.x; acc[5] += xv * m1.y; acc[6] += xv * m1.z; acc[7] += xv * m1.w;
    }
    #pragma unroll
    for (int k = 0; k < NK; k++) atomicAdd(&dz[n][k], acc[k]);  // one-shot, 4-way parts
    __syncthreads();

    // wave 0: softmax over k per row, plus colsum reduction
    if (t < 64) {
        float l[NK];
        float m = -1e30f;
        #pragma unroll
        for (int k = 0; k < NK; k++) { l[k] = FKAPPA * dz[t][k]; m = fmaxf(m, l[k]); }
        float s = 0.f;
        #pragma unroll
        for (int k = 0; k < NK; k++) { l[k] = __expf(l[k] - m); s += l[k]; }
        const float inv = 1.f / s;
        #pragma unroll
        for (int k = 0; k < NK; k++) { l[k] *= inv; dz[t][k] = l[k]; }
        // reduce l over the 64 lanes (= 64 n's) for colsum
        #pragma unroll
        for (int off = 32; off > 0; off >>= 1)
            #pragma unroll
            for (int k = 0; k < NK; k++) l[k] += __shfl_down(l[k], off, 64);
        if (t == 0)
            #pragma unroll
            for (int k = 0; k < NK; k++) atomicAdd(&colsum[b * NK + k], l[k]);
    }
    __syncthreads();

    if (WRITE_Z) {
        if (t < 128)
            reinterpret_cast<float4*>(zout + ((size_t)b * NN + n0) * NK)[t] =
                reinterpret_cast<const float4*>(dz)[t];
    }

    // accumulate phase: thread t = c
    float a2[NK];
    #pragma unroll
    for (int k = 0; k < NK; k++) a2[k] = 0.f;
    #pragma unroll 8
    for (int nn = 0; nn < 64; ++nn) {
        const float xv = xt[nn][t];               // lanes c consecutive: conflict-free
        const float4 z0 = *reinterpret_cast<const float4*>(&dz[nn][0]);   // broadcast
        const float4 z1 = *reinterpret_cast<const float4*>(&dz[nn][4]);
        a2[0] += xv * z0.x; a2[1] += xv * z0.y; a2[2] += xv * z0.z; a2[3] += xv * z0.w;
        a2[4] += xv * z1.x; a2[5] += xv * z1.y; a2[6] += xv * z1.z; a2[7] += xv * z1.w;
    }
    float* np_ = num + (size_t)b * NC * NK + (size_t)t * NK;
    #pragma unroll
    for (int k = 0; k < NK; k++) atomicAdd(&np_[k], a2[k]);
}

// ---------------------------------------------------------------------------
// finalize stage: mu[b,c,k] = l2norm_c( num[b,c,k] / (1e-6+colsum[b,k]) )
// grid: NB blocks, 256 threads (t = c)
__global__ __launch_bounds__(256) void k_newmu(const float* __restrict__ num,
                                               const float* __restrict__ colsum,
                                               float* __restrict__ mu_out) {
    const int b = blockIdx.x;
    const int t = threadIdx.x;
    float inv[NK];
    #pragma unroll
    for (int k = 0; k < NK; k++) inv[k] = 1.f / (1e-6f + colsum[b * NK + k]);

    const float4 v0 = *reinterpret_cast<const float4*>(num + (size_t)b * NC * NK + t * NK);
    const float4 v1 = *reinterpret_cast<const float4*>(num + (size_t)b * NC * NK + t * NK + 4);
    float v[NK] = {v0.x * inv[0], v0.y * inv[1], v0.z * inv[2], v0.w * inv[3],
                   v1.x * inv[4], v1.y * inv[5], v1.z * inv[6], v1.w * inv[7]};

    float sq[NK];
    #pragma unroll
    for (int k = 0; k < NK; k++) sq[k] = v[k] * v[k];
    #pragma unroll
    for (int off = 32; off > 0; off >>= 1)
        #pragma unroll
        for (int k = 0; k < NK; k++) sq[k] += __shfl_down(sq[k], off, 64);

    __shared__ float red[4][NK];
    const int wave = t >> 6, lane = t & 63;
    if (lane == 0)
        #pragma unroll
        for (int k = 0; k < NK; k++) red[wave][k] = sq[k];
    __syncthreads();
    __shared__ float scale[NK];
    if (t < NK) {
        const float tot = red[0][t] + red[1][t] + red[2][t] + red[3][t];
        scale[t] = 1.f / (1e-6f + sqrtf(tot));
    }
    __syncthreads();
    #pragma unroll
    for (int k = 0; k < NK; k++) v[k] *= scale[k];
    *reinterpret_cast<float4*>(mu_out + (size_t)b * NC * NK + t * NK)     = make_float4(v[0], v[1], v[2], v[3]);
    *reinterpret_cast<float4*>(mu_out + (size_t)b * NC * NK + t * NK + 4) = make_float4(v[4], v[5], v[6], v[7]);
}

// ---------------------------------------------------------------------------
// finalize: out0[b,k,c] = mu[b,c,k]
__global__ __launch_bounds__(256) void k_write_mu(const float* __restrict__ mu,
                                                  float* __restrict__ out) {
    const int i = blockIdx.x * 256 + threadIdx.x;
    const int b = i >> 11, r = i & 2047;
    const int k = r >> 8, c = r & 255;
    out[i] = mu[(size_t)b * NC * NK + c * NK + k];
}

// finalize: out1[b,n,k] = z[b,n,k] / (1e-6 + colsum[b,k])
__global__ __launch_bounds__(256) void k_write_z(const float* __restrict__ z,
                                                 const float* __restrict__ colsum,
                                                 float* __restrict__ out) {
    const int i = blockIdx.x * 256 + threadIdx.x;   // 0 .. NB*NN-1
    const int b = i >> 14;
    float inv[NK];
    #pragma unroll
    for (int k = 0; k < NK; k++) inv[k] = 1.f / (1e-6f + colsum[b * NK + k]);
    const float4 z0 = *reinterpret_cast<const float4*>(z + (size_t)i * NK);
    const float4 z1 = *reinterpret_cast<const float4*>(z + (size_t)i * NK + 4);
    *reinterpret_cast<float4*>(out + (size_t)i * NK)     = make_float4(z0.x * inv[0], z0.y * inv[1], z0.z * inv[2], z0.w * inv[3]);
    *reinterpret_cast<float4*>(out + (size_t)i * NK + 4) = make_float4(z1.x * inv[4], z1.y * inv[5], z1.z * inv[6], z1.w * inv[7]);
}

// ---------------------------------------------------------------------------
extern "C" void kernel_launch(void* const* d_in, const int* in_sizes, int n_in,
                              void* d_out, int out_size, void* d_ws, size_t ws_size,
                              hipStream_t stream) {
    const float* x     = (const float*)d_in[0];   // [16,256,128,128]
    const float* mu_in = (const float*)d_in[1];   // [1,256,8]
    float* out = (float*)d_out;                   // mu_f [16*8*256] ++ z_ [16*16384*8]
    char* ws = (char*)d_ws;

    const size_t Z_BYTES   = (size_t)NB * NN * NK * 4;        // 8,388,608
    const size_t CS_BYTES  = (size_t)NSTAGE * NB * NK * 4;    // 5,120
    const size_t NUM_BYTES = (size_t)NSTAGE * NB * NC * NK * 4; // 1,310,720

    float* z      = (float*)ws;
    float* colsum = (float*)(ws + Z_BYTES);
    float* num    = (float*)(ws + Z_BYTES + CS_BYTES);
    float* mu_a   = (float*)(ws + Z_BYTES + CS_BYTES + NUM_BYTES);

    // zero the per-stage accumulators (colsum + num are contiguous)
    hipMemsetAsync(colsum, 0, CS_BYTES + NUM_BYTES, stream);
    k_init_mu<<<NB * NC * NK / 256, 256, 0, stream>>>(mu_in, mu_a);

    for (int s = 0; s < NSTAGE; ++s) {
        float* cs = colsum + s * NB * NK;
        float* nm = num + (size_t)s * NB * NC * NK;
        if (s == NSTAGE - 1)
            k_stage<true><<<NB * 256, 256, 0, stream>>>(x, mu_a, nm, cs, z);
        else
            k_stage<false><<<NB * 256, 256, 0, stream>>>(x, mu_a, nm, cs, z);
        k_newmu<<<NB, 256, 0, stream>>>(nm, cs, mu_a);
    }

    k_write_mu<<<NB * NK * NC / 256, 256, 0, stream>>>(mu_a, out);
    k_write_z<<<NB * NN / 256, 256, 0, stream>>>(z, colsum + (NSTAGE - 1) * NB * NK,
                                                 out + NB * NK * NC);
}

// Round 5
// 4672.802 us; speedup vs baseline: 1.0689x; 1.0689x over previous
//
#include <hip/hip_runtime.h>
#include <hip/hip_fp16.h>
#include <cstdint>
#include <cstddef>

#define NB 16
#define NC 256
#define NK 8
#define NN 16384
#define NSTAGE 10
#define FKAPPA 20.0f
#define NT 64              // n-tile per block -> 256 tiles per batch

// ---------------------------------------------------------------------------
// init: broadcast mu_in [C*K] -> mu_cur [B][C][K]
__global__ __launch_bounds__(256) void k_init_mu(const float* __restrict__ mu_in,
                                                 float* __restrict__ mu_cur) {
    int i = blockIdx.x * 256 + threadIdx.x;
    mu_cur[i] = mu_in[i & (NC * NK - 1)];
}

// ---------------------------------------------------------------------------
// Fused stage, one x-read per stage. Block = (b, 64-n tile), 256 threads.
// Phase 1: float4 global x loads -> fp16 LDS tile + fp32 dot vs LDS mu.
//          reduce partials: shfl-xor (lanes ^16,^32), LDS atomics into dz.
// softmax: wave 0, n = lane; colsum global atomics. (z -> zT global on last)
// Phase 2: thread = c; num[c][k] += fp16(x[c,n]) * z[n,k], z via broadcast
//          float4 reads from dz[n][12-padded]; 8 global atomics per thread.
template <bool WRITE_Z>
__global__ __launch_bounds__(256) void k_stage(const float* __restrict__ x,
                                               const float* __restrict__ mu,
                                               float* __restrict__ num,
                                               float* __restrict__ colsum,
                                               float* __restrict__ zT) {
    const int b    = blockIdx.x >> 8;
    const int nt   = blockIdx.x & 255;
    const int t    = threadIdx.x;
    const int lane = t & 63;
    const int wv   = t >> 6;

    __shared__ __align__(16) __half xt[NC][66];   // 33792 B, 66-stride: 2-way banks
    __shared__ __align__(16) float  smu[NC * NK]; // 8192 B
    __shared__ __align__(16) float  dz[NT][12];   // 3072 B, rows 48 B (f4-aligned)

    for (int i = t; i < NC * NK; i += 256) smu[i] = mu[b * NC * NK + i];
    {
        float4* p = (float4*)dz;
        for (int i = t; i < NT * 12 / 4; i += 256) p[i] = make_float4(0.f, 0.f, 0.f, 0.f);
    }
    __syncthreads();

    const int nl = (lane & 15) * 4;     // n offset within tile (float4)
    const int cg = lane >> 4;           // 4 c-rows per wave-instruction
    const int n0 = nt * NT;
    const float* xp = x + (size_t)b * NC * NN + n0 + nl;

    float acc[4][NK];
    #pragma unroll
    for (int i = 0; i < 4; i++)
        #pragma unroll
        for (int k = 0; k < NK; k++) acc[i][k] = 0.f;

    #pragma unroll 8
    for (int ci = 0; ci < 16; ++ci) {
        const int c = wv * 64 + ci * 4 + cg;
        const float4 xv = *reinterpret_cast<const float4*>(xp + (size_t)c * NN);
        *reinterpret_cast<__half2*>(&xt[c][nl])     = __floats2half2_rn(xv.x, xv.y);
        *reinterpret_cast<__half2*>(&xt[c][nl + 2]) = __floats2half2_rn(xv.z, xv.w);
        const float4 m0 = *reinterpret_cast<const float4*>(&smu[c * NK]);
        const float4 m1 = *reinterpret_cast<const float4*>(&smu[c * NK + 4]);
        acc[0][0] += xv.x * m0.x; acc[0][1] += xv.x * m0.y; acc[0][2] += xv.x * m0.z; acc[0][3] += xv.x * m0.w;
        acc[0][4] += xv.x * m1.x; acc[0][5] += xv.x * m1.y; acc[0][6] += xv.x * m1.z; acc[0][7] += xv.x * m1.w;
        acc[1][0] += xv.y * m0.x; acc[1][1] += xv.y * m0.y; acc[1][2] += xv.y * m0.z; acc[1][3] += xv.y * m0.w;
        acc[1][4] += xv.y * m1.x; acc[1][5] += xv.y * m1.y; acc[1][6] += xv.y * m1.z; acc[1][7] += xv.y * m1.w;
        acc[2][0] += xv.z * m0.x; acc[2][1] += xv.z * m0.y; acc[2][2] += xv.z * m0.z; acc[2][3] += xv.z * m0.w;
        acc[2][4] += xv.z * m1.x; acc[2][5] += xv.z * m1.y; acc[2][6] += xv.z * m1.z; acc[2][7] += xv.z * m1.w;
        acc[3][0] += xv.w * m0.x; acc[3][1] += xv.w * m0.y; acc[3][2] += xv.w * m0.z; acc[3][3] += xv.w * m0.w;
        acc[3][4] += xv.w * m1.x; acc[3][5] += xv.w * m1.y; acc[3][6] += xv.w * m1.z; acc[3][7] += xv.w * m1.w;
    }

    // reduce the 4 c-groups within the wave (lanes ^16, ^32 share nl)
    #pragma unroll
    for (int m = 16; m <= 32; m <<= 1)
        #pragma unroll
        for (int i = 0; i < 4; i++)
            #pragma unroll
            for (int k = 0; k < NK; k++) acc[i][k] += __shfl_xor(acc[i][k], m, 64);

    if (lane < 16) {   // lanes 0..15 hold this wave's full-64-c partials
        #pragma unroll
        for (int i = 0; i < 4; i++)
            #pragma unroll
            for (int k = 0; k < NK; k++) atomicAdd(&dz[nl + i][k], acc[i][k]);
    }
    __syncthreads();

    // softmax over k per n (wave 0 only, t = n), colsum, optional z output
    if (t < NT) {
        float l[NK];
        float mx = -1e30f;
        #pragma unroll
        for (int k = 0; k < NK; k++) { l[k] = FKAPPA * dz[t][k]; mx = fmaxf(mx, l[k]); }
        float s = 0.f;
        #pragma unroll
        for (int k = 0; k < NK; k++) { l[k] = __expf(l[k] - mx); s += l[k]; }
        const float inv = 1.f / s;
        #pragma unroll
        for (int k = 0; k < NK; k++) { l[k] *= inv; dz[t][k] = l[k]; }
        if (WRITE_Z) {
            #pragma unroll
            for (int k = 0; k < NK; k++)
                zT[((size_t)b * NK + k) * NN + n0 + t] = l[k];
        }
        #pragma unroll
        for (int off = 32; off > 0; off >>= 1)
            #pragma unroll
            for (int k = 0; k < NK; k++) l[k] += __shfl_down(l[k], off, 64);
        if (t == 0)
            #pragma unroll
            for (int k = 0; k < NK; k++) atomicAdd(&colsum[b * NK + k], l[k]);
    }
    __syncthreads();

    // phase 2: thread t = c; acc over the tile's 64 n
    float a2[NK];
    #pragma unroll
    for (int k = 0; k < NK; k++) a2[k] = 0.f;

    #pragma unroll 8
    for (int j = 0; j < NT / 2; ++j) {
        const __half2 xh = *reinterpret_cast<const __half2*>(&xt[t][2 * j]);
        const float2 xf = __half22float2(xh);
        const float4 za0 = *reinterpret_cast<const float4*>(&dz[2 * j][0]);
        const float4 za1 = *reinterpret_cast<const float4*>(&dz[2 * j][4]);
        const float4 zb0 = *reinterpret_cast<const float4*>(&dz[2 * j + 1][0]);
        const float4 zb1 = *reinterpret_cast<const float4*>(&dz[2 * j + 1][4]);
        a2[0] += xf.x * za0.x + xf.y * zb0.x;
        a2[1] += xf.x * za0.y + xf.y * zb0.y;
        a2[2] += xf.x * za0.z + xf.y * zb0.z;
        a2[3] += xf.x * za0.w + xf.y * zb0.w;
        a2[4] += xf.x * za1.x + xf.y * zb1.x;
        a2[5] += xf.x * za1.y + xf.y * zb1.y;
        a2[6] += xf.x * za1.z + xf.y * zb1.z;
        a2[7] += xf.x * za1.w + xf.y * zb1.w;
    }
    float* np_ = num + ((size_t)b * NC + t) * NK;
    #pragma unroll
    for (int k = 0; k < NK; k++) atomicAdd(&np_[k], a2[k]);
}

// ---------------------------------------------------------------------------
// mu[b,c,k] = l2norm_c( num[b,c,k] / (1e-6+colsum[b,k]) ); grid NB, t = c
__global__ __launch_bounds__(256) void k_newmu(const float* __restrict__ num,
                                               const float* __restrict__ colsum,
                                               float* __restrict__ mu_out) {
    const int b = blockIdx.x;
    const int t = threadIdx.x;
    float inv[NK];
    #pragma unroll
    for (int k = 0; k < NK; k++) inv[k] = 1.f / (1e-6f + colsum[b * NK + k]);

    const float4 v0 = *reinterpret_cast<const float4*>(num + (size_t)b * NC * NK + t * NK);
    const float4 v1 = *reinterpret_cast<const float4*>(num + (size_t)b * NC * NK + t * NK + 4);
    float v[NK] = {v0.x * inv[0], v0.y * inv[1], v0.z * inv[2], v0.w * inv[3],
                   v1.x * inv[4], v1.y * inv[5], v1.z * inv[6], v1.w * inv[7]};

    float sq[NK];
    #pragma unroll
    for (int k = 0; k < NK; k++) sq[k] = v[k] * v[k];
    #pragma unroll
    for (int off = 32; off > 0; off >>= 1)
        #pragma unroll
        for (int k = 0; k < NK; k++) sq[k] += __shfl_down(sq[k], off, 64);

    __shared__ float red[4][NK];
    const int wave = t >> 6, lane = t & 63;
    if (lane == 0)
        #pragma unroll
        for (int k = 0; k < NK; k++) red[wave][k] = sq[k];
    __syncthreads();
    __shared__ float scale[NK];
    if (t < NK) {
        const float tot = red[0][t] + red[1][t] + red[2][t] + red[3][t];
        scale[t] = 1.f / (1e-6f + sqrtf(tot));
    }
    __syncthreads();
    #pragma unroll
    for (int k = 0; k < NK; k++) v[k] *= scale[k];
    *reinterpret_cast<float4*>(mu_out + (size_t)b * NC * NK + t * NK)     = make_float4(v[0], v[1], v[2], v[3]);
    *reinterpret_cast<float4*>(mu_out + (size_t)b * NC * NK + t * NK + 4) = make_float4(v[4], v[5], v[6], v[7]);
}

// ---------------------------------------------------------------------------
// out0[b,k,c] = mu[b,c,k]
__global__ __launch_bounds__(256) void k_write_mu(const float* __restrict__ mu,
                                                  float* __restrict__ out) {
    const int i = blockIdx.x * 256 + threadIdx.x;
    const int b = i >> 11, r = i & 2047;
    const int k = r >> 8, c = r & 255;
    out[i] = mu[(size_t)b * NC * NK + c * NK + k];
}

// out1[b,n,k] = zT[b,k,n] / (1e-6 + colsum[b,k]); thread = 4-n group
__global__ __launch_bounds__(256) void k_write_z(const float* __restrict__ zT,
                                                 const float* __restrict__ colsum,
                                                 float* __restrict__ out) {
    const int i = blockIdx.x * 256 + threadIdx.x;   // 0 .. NB*NN/4-1
    const int b = i >> 12;
    const int n4 = (i & 4095) * 4;
    float inv[NK];
    #pragma unroll
    for (int k = 0; k < NK; k++) inv[k] = 1.f / (1e-6f + colsum[b * NK + k]);

    float zc[NK][4];
    #pragma unroll
    for (int k = 0; k < NK; k++) {
        const float4 v = *reinterpret_cast<const float4*>(zT + ((size_t)b * NK + k) * NN + n4);
        zc[k][0] = v.x * inv[k]; zc[k][1] = v.y * inv[k];
        zc[k][2] = v.z * inv[k]; zc[k][3] = v.w * inv[k];
    }
    float* op = out + ((size_t)b * NN + n4) * NK;
    #pragma unroll
    for (int j = 0; j < 4; ++j) {
        *reinterpret_cast<float4*>(op + j * NK)     = make_float4(zc[0][j], zc[1][j], zc[2][j], zc[3][j]);
        *reinterpret_cast<float4*>(op + j * NK + 4) = make_float4(zc[4][j], zc[5][j], zc[6][j], zc[7][j]);
    }
}

// ---------------------------------------------------------------------------
extern "C" void kernel_launch(void* const* d_in, const int* in_sizes, int n_in,
                              void* d_out, int out_size, void* d_ws, size_t ws_size,
                              hipStream_t stream) {
    const float* x     = (const float*)d_in[0];   // [16,256,128,128]
    const float* mu_in = (const float*)d_in[1];   // [1,256,8]
    float* out = (float*)d_out;                   // mu_f [16*8*256] ++ z_ [16*16384*8]
    char* ws = (char*)d_ws;

    const size_t ZT_BYTES  = (size_t)NB * NK * NN * 4;          // 8,388,608
    const size_t CS_BYTES  = (size_t)NSTAGE * NB * NK * 4;      // 5,120
    const size_t NUM_BYTES = (size_t)NSTAGE * NB * NC * NK * 4; // 1,310,720

    float* zT     = (float*)ws;
    float* colsum = (float*)(ws + ZT_BYTES);
    float* num    = (float*)(ws + ZT_BYTES + CS_BYTES);
    float* mu_a   = (float*)(ws + ZT_BYTES + CS_BYTES + NUM_BYTES);

    hipMemsetAsync(colsum, 0, CS_BYTES + NUM_BYTES, stream);
    k_init_mu<<<NB * NC * NK / 256, 256, 0, stream>>>(mu_in, mu_a);

    for (int s = 0; s < NSTAGE; ++s) {
        float* cs = colsum + s * NB * NK;
        float* nm = num + (size_t)s * NB * NC * NK;
        if (s == NSTAGE - 1)
            k_stage<true><<<NB * 256, 256, 0, stream>>>(x, mu_a, nm, cs, zT);
        else
            k_stage<false><<<NB * 256, 256, 0, stream>>>(x, mu_a, nm, cs, zT);
        k_newmu<<<NB, 256, 0, stream>>>(nm, cs, mu_a);
    }

    k_write_mu<<<NB * NK * NC / 256, 256, 0, stream>>>(mu_a, out);
    k_write_z<<<NB * NN / 4 / 256, 256, 0, stream>>>(zT, colsum + (NSTAGE - 1) * NB * NK,
                                                     out + NB * NK * NC);
}

// Round 7
// 1688.278 us; speedup vs baseline: 2.9586x; 2.7678x over previous
//
#include <hip/hip_runtime.h>
#include <hip/hip_fp16.h>
#include <cstdint>
#include <cstddef>

#define NB 16
#define NC 256
#define NK 8
#define NN 16384
#define NSTAGE 10
#define FKAPPA 20.0f
#define NT 64              // n per tile
#define TPB 2              // tiles per block -> 128 n per block
#define NBLK 128           // blocks per batch (128 * 128 n = 16384)

// ---------------------------------------------------------------------------
// init: broadcast mu_in [C*K] -> mu_cur [B][C][K]
__global__ __launch_bounds__(256) void k_init_mu(const float* __restrict__ mu_in,
                                                 float* __restrict__ mu_cur) {
    int i = blockIdx.x * 256 + threadIdx.x;
    mu_cur[i] = mu_in[i & (NC * NK - 1)];
}

// ---------------------------------------------------------------------------
// Fused stage, atomic-free. Block = (b, 2x 64-n tiles), 256 threads.
// Per tile: float4 x loads -> fp16 LDS tile + fp32 dot vs LDS mu;
//           shfl-xor partial fold + LDS atomics into dz; wave0 softmax;
//           phase2 accumulates a2[c][k] in registers across tiles.
// End: non-atomic partial writes: part[bx][c][k], cspart[bx][k].
template <bool WRITE_Z>
__global__ __launch_bounds__(256) void k_stage(const float* __restrict__ x,
                                               const float* __restrict__ mu,
                                               float* __restrict__ part,
                                               float* __restrict__ cspart,
                                               float* __restrict__ zraw) {
    const int b    = blockIdx.x >> 7;
    const int nt2  = blockIdx.x & (NBLK - 1);
    const int t    = threadIdx.x;
    const int lane = t & 63;
    const int wv   = t >> 6;

    __shared__ __align__(16) __half xt[NC][66];   // 33792 B
    __shared__ __align__(16) float  smu[NC * NK]; // 8192 B
    __shared__ __align__(16) float  dz[NT][12];   // 3072 B

    for (int i = t; i < NC * NK; i += 256) smu[i] = mu[b * NC * NK + i];

    const int nl = (lane & 15) * 4;
    const int cg = lane >> 4;

    float a2[NK];
    float csk[NK];
    #pragma unroll
    for (int k = 0; k < NK; k++) { a2[k] = 0.f; csk[k] = 0.f; }

    for (int g = 0; g < TPB; ++g) {
        const int n0 = (nt2 * TPB + g) * NT;
        __syncthreads();                       // protect xt/dz from prev phase2
        if (t < NT * 12 / 4)
            reinterpret_cast<float4*>(dz)[t] = make_float4(0.f, 0.f, 0.f, 0.f);
        __syncthreads();

        const float* xp = x + (size_t)b * NC * NN + n0 + nl;
        float acc[4][NK];
        #pragma unroll
        for (int i = 0; i < 4; i++)
            #pragma unroll
            for (int k = 0; k < NK; k++) acc[i][k] = 0.f;

        #pragma unroll 8
        for (int ci = 0; ci < 16; ++ci) {
            const int c = wv * 64 + ci * 4 + cg;
            const float4 xv = *reinterpret_cast<const float4*>(xp + (size_t)c * NN);
            *reinterpret_cast<__half2*>(&xt[c][nl])     = __floats2half2_rn(xv.x, xv.y);
            *reinterpret_cast<__half2*>(&xt[c][nl + 2]) = __floats2half2_rn(xv.z, xv.w);
            const float4 m0 = *reinterpret_cast<const float4*>(&smu[c * NK]);
            const float4 m1 = *reinterpret_cast<const float4*>(&smu[c * NK + 4]);
            acc[0][0] += xv.x * m0.x; acc[0][1] += xv.x * m0.y; acc[0][2] += xv.x * m0.z; acc[0][3] += xv.x * m0.w;
            acc[0][4] += xv.x * m1.x; acc[0][5] += xv.x * m1.y; acc[0][6] += xv.x * m1.z; acc[0][7] += xv.x * m1.w;
            acc[1][0] += xv.y * m0.x; acc[1][1] += xv.y * m0.y; acc[1][2] += xv.y * m0.z; acc[1][3] += xv.y * m0.w;
            acc[1][4] += xv.y * m1.x; acc[1][5] += xv.y * m1.y; acc[1][6] += xv.y * m1.z; acc[1][7] += xv.y * m1.w;
            acc[2][0] += xv.z * m0.x; acc[2][1] += xv.z * m0.y; acc[2][2] += xv.z * m0.z; acc[2][3] += xv.z * m0.w;
            acc[2][4] += xv.z * m1.x; acc[2][5] += xv.z * m1.y; acc[2][6] += xv.z * m1.z; acc[2][7] += xv.z * m1.w;
            acc[3][0] += xv.w * m0.x; acc[3][1] += xv.w * m0.y; acc[3][2] += xv.w * m0.z; acc[3][3] += xv.w * m0.w;
            acc[3][4] += xv.w * m1.x; acc[3][5] += xv.w * m1.y; acc[3][6] += xv.w * m1.z; acc[3][7] += xv.w * m1.w;
        }

        #pragma unroll
        for (int m = 16; m <= 32; m <<= 1)
            #pragma unroll
            for (int i = 0; i < 4; i++)
                #pragma unroll
                for (int k = 0; k < NK; k++) acc[i][k] += __shfl_xor(acc[i][k], m, 64);

        if (lane < 16) {
            #pragma unroll
            for (int i = 0; i < 4; i++)
                #pragma unroll
                for (int k = 0; k < NK; k++) atomicAdd(&dz[nl + i][k], acc[i][k]);
        }
        __syncthreads();

        if (t < NT) {
            float l[NK];
            float mx = -1e30f;
            #pragma unroll
            for (int k = 0; k < NK; k++) { l[k] = FKAPPA * dz[t][k]; mx = fmaxf(mx, l[k]); }
            float s = 0.f;
            #pragma unroll
            for (int k = 0; k < NK; k++) { l[k] = __expf(l[k] - mx); s += l[k]; }
            const float inv = 1.f / s;
            #pragma unroll
            for (int k = 0; k < NK; k++) { l[k] *= inv; dz[t][k] = l[k]; }
            if (WRITE_Z) {
                float* zp = zraw + ((size_t)b * NN + n0 + t) * NK;
                *reinterpret_cast<float4*>(zp)     = make_float4(l[0], l[1], l[2], l[3]);
                *reinterpret_cast<float4*>(zp + 4) = make_float4(l[4], l[5], l[6], l[7]);
            }
            #pragma unroll
            for (int off = 32; off > 0; off >>= 1)
                #pragma unroll
                for (int k = 0; k < NK; k++) l[k] += __shfl_down(l[k], off, 64);
            #pragma unroll
            for (int k = 0; k < NK; k++) csk[k] += l[k];    // lane 0 meaningful
        }
        __syncthreads();

        // phase 2: thread t = c
        #pragma unroll 8
        for (int j = 0; j < NT / 2; ++j) {
            const __half2 xh = *reinterpret_cast<const __half2*>(&xt[t][2 * j]);
            const float2 xf = __half22float2(xh);
            const float4 za0 = *reinterpret_cast<const float4*>(&dz[2 * j][0]);
            const float4 za1 = *reinterpret_cast<const float4*>(&dz[2 * j][4]);
            const float4 zb0 = *reinterpret_cast<const float4*>(&dz[2 * j + 1][0]);
            const float4 zb1 = *reinterpret_cast<const float4*>(&dz[2 * j + 1][4]);
            a2[0] += xf.x * za0.x + xf.y * zb0.x;
            a2[1] += xf.x * za0.y + xf.y * zb0.y;
            a2[2] += xf.x * za0.z + xf.y * zb0.z;
            a2[3] += xf.x * za0.w + xf.y * zb0.w;
            a2[4] += xf.x * za1.x + xf.y * zb1.x;
            a2[5] += xf.x * za1.y + xf.y * zb1.y;
            a2[6] += xf.x * za1.z + xf.y * zb1.z;
            a2[7] += xf.x * za1.w + xf.y * zb1.w;
        }
    }

    float* pp = part + (size_t)blockIdx.x * (NC * NK) + t * NK;
    *reinterpret_cast<float4*>(pp)     = make_float4(a2[0], a2[1], a2[2], a2[3]);
    *reinterpret_cast<float4*>(pp + 4) = make_float4(a2[4], a2[5], a2[6], a2[7]);
    if (t == 0) {
        #pragma unroll
        for (int k = 0; k < NK; k++) cspart[blockIdx.x * NK + k] = csk[k];
    }
}

// ---------------------------------------------------------------------------
// reduce partials: num[b,ck] = sum_g part[b,g,ck]; colsum[b,k] = sum_g cspart
// grid: NB*8 blocks, 256 threads
__global__ __launch_bounds__(256) void k_reduce(const float* __restrict__ part,
                                                const float* __restrict__ cspart,
                                                float* __restrict__ num,
                                                float* __restrict__ colsum) {
    const int b  = blockIdx.x >> 3;
    const int cg = blockIdx.x & 7;
    const int t  = threadIdx.x;
    const int ck = cg * 256 + t;

    float s = 0.f;
    const float* p = part + (size_t)b * NBLK * (NC * NK) + ck;
    #pragma unroll 8
    for (int g = 0; g < NBLK; ++g) s += p[(size_t)g * (NC * NK)];
    num[b * (NC * NK) + ck] = s;

    __shared__ float cred[2][NK];
    if (cg == 0 && t < NBLK) {
        const float4 u0 = *reinterpret_cast<const float4*>(&cspart[(b * NBLK + t) * NK]);
        const float4 u1 = *reinterpret_cast<const float4*>(&cspart[(b * NBLK + t) * NK + 4]);
        float v[NK] = {u0.x, u0.y, u0.z, u0.w, u1.x, u1.y, u1.z, u1.w};
        #pragma unroll
        for (int off = 32; off > 0; off >>= 1)
            #pragma unroll
            for (int k = 0; k < NK; k++) v[k] += __shfl_down(v[k], off, 64);
        if ((t & 63) == 0)
            #pragma unroll
            for (int k = 0; k < NK; k++) cred[t >> 6][k] = v[k];
    }
    __syncthreads();
    if (cg == 0 && t < NK) colsum[b * NK + t] = cred[0][t] + cred[1][t];
}

// ---------------------------------------------------------------------------
// mu[b,c,k] = l2norm_c( num[b,c,k] / (1e-6+colsum[b,k]) ); grid NB, t = c
__global__ __launch_bounds__(256) void k_newmu(const float* __restrict__ num,
                                               const float* __restrict__ colsum,
                                               float* __restrict__ mu_out) {
    const int b = blockIdx.x;
    const int t = threadIdx.x;
    float inv[NK];
    #pragma unroll
    for (int k = 0; k < NK; k++) inv[k] = 1.f / (1e-6f + colsum[b * NK + k]);

    const float4 v0 = *reinterpret_cast<const float4*>(num + (size_t)b * NC * NK + t * NK);
    const float4 v1 = *reinterpret_cast<const float4*>(num + (size_t)b * NC * NK + t * NK + 4);
    float v[NK] = {v0.x * inv[0], v0.y * inv[1], v0.z * inv[2], v0.w * inv[3],
                   v1.x * inv[4], v1.y * inv[5], v1.z * inv[6], v1.w * inv[7]};

    float sq[NK];
    #pragma unroll
    for (int k = 0; k < NK; k++) sq[k] = v[k] * v[k];
    #pragma unroll
    for (int off = 32; off > 0; off >>= 1)
        #pragma unroll
        for (int k = 0; k < NK; k++) sq[k] += __shfl_down(sq[k], off, 64);

    __shared__ float red[4][NK];
    const int wave = t >> 6, lane = t & 63;
    if (lane == 0)
        #pragma unroll
        for (int k = 0; k < NK; k++) red[wave][k] = sq[k];
    __syncthreads();
    __shared__ float scale[NK];
    if (t < NK) {
        const float tot = red[0][t] + red[1][t] + red[2][t] + red[3][t];
        scale[t] = 1.f / (1e-6f + sqrtf(tot));
    }
    __syncthreads();
    #pragma unroll
    for (int k = 0; k < NK; k++) v[k] *= scale[k];
    *reinterpret_cast<float4*>(mu_out + (size_t)b * NC * NK + t * NK)     = make_float4(v[0], v[1], v[2], v[3]);
    *reinterpret_cast<float4*>(mu_out + (size_t)b * NC * NK + t * NK + 4) = make_float4(v[4], v[5], v[6], v[7]);
}

// ---------------------------------------------------------------------------
// out0[b,k,c] = mu[b,c,k]
__global__ __launch_bounds__(256) void k_write_mu(const float* __restrict__ mu,
                                                  float* __restrict__ out) {
    const int i = blockIdx.x * 256 + threadIdx.x;
    const int b = i >> 11, r = i & 2047;
    const int k = r >> 8, c = r & 255;
    out[i] = mu[(size_t)b * NC * NK + c * NK + k];
}

// in-place: out1[b,n,k] /= (1e-6 + colsum[b,k]); thread = 4-n group
__global__ __launch_bounds__(256) void k_write_z(const float* __restrict__ colsum,
                                                 float* __restrict__ out1) {
    const int i = blockIdx.x * 256 + threadIdx.x;   // 0 .. NB*NN/4-1
    const int b = i >> 12;
    const int n4 = (i & 4095) * 4;
    float inv[NK];
    #pragma unroll
    for (int k = 0; k < NK; k++) inv[k] = 1.f / (1e-6f + colsum[b * NK + k]);

    float4* p = reinterpret_cast<float4*>(out1 + ((size_t)b * NN + n4) * NK);
    #pragma unroll
    for (int j = 0; j < 4; ++j) {
        float4 a = p[2 * j], c = p[2 * j + 1];
        a.x *= inv[0]; a.y *= inv[1]; a.z *= inv[2]; a.w *= inv[3];
        c.x *= inv[4]; c.y *= inv[5]; c.z *= inv[6]; c.w *= inv[7];
        p[2 * j] = a; p[2 * j + 1] = c;
    }
}

// ---------------------------------------------------------------------------
extern "C" void kernel_launch(void* const* d_in, const int* in_sizes, int n_in,
                              void* d_out, int out_size, void* d_ws, size_t ws_size,
                              hipStream_t stream) {
    const float* x     = (const float*)d_in[0];   // [16,256,128,128]
    const float* mu_in = (const float*)d_in[1];   // [1,256,8]
    float* out  = (float*)d_out;                  // mu_f [16*8*256] ++ z_ [16*16384*8]
    float* out1 = out + NB * NK * NC;
    char* ws = (char*)d_ws;

    const size_t PART_BYTES = (size_t)NB * NBLK * NC * NK * 4;  // 16,777,216
    const size_t CSP_BYTES  = (size_t)NB * NBLK * NK * 4;       // 65,536
    const size_t NUM_BYTES  = (size_t)NB * NC * NK * 4;         // 131,072
    const size_t CS_BYTES   = (size_t)NB * NK * 4;              // 512

    float* part   = (float*)ws;
    float* cspart = (float*)(ws + PART_BYTES);
    float* num    = (float*)(ws + PART_BYTES + CSP_BYTES);
    float* colsum = (float*)(ws + PART_BYTES + CSP_BYTES + NUM_BYTES);
    float* mu_a   = (float*)(ws + PART_BYTES + CSP_BYTES + NUM_BYTES + CS_BYTES);

    k_init_mu<<<NB * NC * NK / 256, 256, 0, stream>>>(mu_in, mu_a);

    for (int s = 0; s < NSTAGE; ++s) {
        if (s == NSTAGE - 1)
            k_stage<true><<<NB * NBLK, 256, 0, stream>>>(x, mu_a, part, cspart, out1);
        else
            k_stage<false><<<NB * NBLK, 256, 0, stream>>>(x, mu_a, part, cspart, out1);
        k_reduce<<<NB * 8, 256, 0, stream>>>(part, cspart, num, colsum);
        k_newmu<<<NB, 256, 0, stream>>>(num, colsum, mu_a);
    }

    k_write_mu<<<NB * NK * NC / 256, 256, 0, stream>>>(mu_a, out);
    k_write_z<<<NB * NN / 4 / 256, 256, 0, stream>>>(colsum, out1);
}